// Round 1
// baseline (182.582 us; speedup 1.0000x reference)
//
#include <hip/hip_runtime.h>

// Problem constants (from reference): B=16384, D=255, K=4, L=16, T=1020
constexpr int T_TUN = 1020;
constexpr int D_DST = 255;
constexpr int L_LNK = 16;
constexpr float EPS = 1e-8f;
constexpr int ROWS_PER_BLOCK = 8;   // 4 waves x 2 rows

__device__ __forceinline__ float read_lane_f(float v, int l) {
  return __builtin_bit_cast(float,
      __builtin_amdgcn_readlane(__builtin_bit_cast(int, v), l));
}

__global__ __launch_bounds__(256) void rowloss_kernel(
    const float* __restrict__ pred,     // [B, T]
    const float* __restrict__ demands,  // [B, D]
    const float* __restrict__ cur,      // [B, L]
    const float* __restrict__ caps,     // [L]
    const int*   __restrict__ t2l,      // [T]
    float* __restrict__ partials)       // [gridDim.x]
{
  const int tid  = threadIdx.x;
  const int lane = tid & 63;
  const int w    = tid >> 6;   // wave id 0..3

  // Bin-major per-lane bins: priv[link*64 + lane].
  //  - scatter: ds_add_f32 (no-return LDS atomic) -> NO serialized RMW chain.
  //    bank = lane&31 -> 2-way (free); cross-lane collisions impossible.
  //  - column reduce: lane's 16 copies are CONSECUTIVE -> 4x ds_read_b128
  __shared__ float priv_all[4][L_LNK * 64];   // 4 KB/wave, 16 KB/block
  __shared__ float wacc[4];
  float* priv = priv_all[w];

  const int b16 = lane & 15;       // this lane's bin for the reduce/stats
  const int g   = lane >> 4;       // lane group 0..3
  const float capinv = 1.0f / (caps[b16] + EPS);

  // Row-invariant scatter offsets: element index = link*64 + lane
  int off[4][4];
  bool dv[4];
#pragma unroll
  for (int j = 0; j < 4; ++j) {
    const int d = lane + 64 * j;
    dv[j] = (d < D_DST);
    const int dd = dv[j] ? d : 0;
    const int4 lk = ((const int4*)t2l)[dd];   // t2l[4d..4d+3]
    off[j][0] = lk.x * 64 + lane;
    off[j][1] = lk.y * 64 + lane;
    off[j][2] = lk.z * 64 + lane;
    off[j][3] = lk.w * 64 + lane;
  }

  const int row0 = blockIdx.x * ROWS_PER_BLOCK + w * 2;

  // ---- issue ALL global loads for both rows up front (max MLP) ----
  float4 r4[2][4];
  float  dm[2][4];
  float  mycur[2];
#pragma unroll
  for (int r = 0; r < 2; ++r) {
    const int b = row0 + r;
    const float4* prow = (const float4*)(pred + (size_t)b * T_TUN);
    const float*  drow = demands + (size_t)b * D_DST;
    mycur[r] = cur[(size_t)b * L_LNK + b16];
#pragma unroll
    for (int j = 0; j < 4; ++j) {
      const int d = lane + 64 * j;
      if (dv[j]) { r4[r][j] = prow[d]; dm[r][j] = drow[d]; }
    }
  }

  float acc = 0.0f;

#pragma unroll
  for (int r = 0; r < 2; ++r) {
    __builtin_amdgcn_wave_barrier();  // keep zero-writes after prior row's reads

    // zero the wave's 1024-float region: 4x ds_write_b128
    {
      const float4 z = make_float4(0.f, 0.f, 0.f, 0.f);
      float4* pz = (float4*)priv;
#pragma unroll
      for (int i = 0; i < 4; ++i) pz[lane + 64 * i] = z;
    }

    __builtin_amdgcn_wave_barrier();  // zeroes complete before atomics land

    // scatter: fire-and-forget ds_add_f32 into lane-distinct slots.
    // No read-back -> no dependent chain; 16 independent DS ops.
#pragma unroll
    for (int j = 0; j < 4; ++j) {
      if (!dv[j]) continue;            // only lane63/j3 diverges
      const float4 v = r4[r][j];
      const float  d = dm[r][j];
      atomicAdd(&priv[off[j][0]], v.x * d);
      atomicAdd(&priv[off[j][1]], v.y * d);
      atomicAdd(&priv[off[j][2]], v.z * d);
      atomicAdd(&priv[off[j][3]], v.w * d);
    }

    __builtin_amdgcn_wave_barrier();  // keep reduce reads after scatter adds

    // column reduce: lane's 16 copies (16g..16g+15 of bin b16) = 4x b128
    float cs = 0.0f;
    {
      const float4* pr = (const float4*)(priv + b16 * 64 + 16 * g);
#pragma unroll
      for (int q = 0; q < 4; ++q) {
        const float4 v = pr[q];
        cs += v.x + v.y + v.z + v.w;
      }
    }
    cs += __shfl_xor(cs, 16, 64);
    cs += __shfl_xor(cs, 32, 64);

    const float u = cs * capinv;

    // fused stats: group 0 sums u, 1 sums u^2, 2 sums u*cur, 3 maxes u
    float val = (g == 0) ? u : (g == 1) ? (u * u)
              : (g == 2) ? (u * mycur[r]) : u;
#pragma unroll
    for (int m = 1; m < 16; m <<= 1) {
      const float o  = __shfl_xor(val, m, 64);
      const float sm = val + o;
      const float mm = fmaxf(val, o);
      val = (g == 3) ? mm : sm;
    }
    const float s1 = read_lane_f(val, 0);
    const float s2 = read_lane_f(val, 16);
    const float s3 = read_lane_f(val, 32);
    const float mx = read_lane_f(val, 48);
    const float var = (s2 - s1 * s1 * (1.0f / 16.0f)) * (1.0f / 15.0f); // ddof=1
    acc += 0.3f * var + 0.5f * s3 + 0.2f * mx;
  }

  if (lane == 0) wacc[w] = acc;
  __syncthreads();
  if (tid == 0) partials[blockIdx.x] = wacc[0] + wacc[1] + wacc[2] + wacc[3];
}

__global__ __launch_bounds__(256) void reduce_kernel(
    const float* __restrict__ partials, int n, float* __restrict__ out, float invB)
{
  __shared__ float s[256];
  const int tid = threadIdx.x;
  const float4* p4 = (const float4*)partials;
  const int n4 = n >> 2;
  float a = 0.0f;
  for (int i = tid; i < n4; i += 256) {
    const float4 v = p4[i];
    a += v.x + v.y + v.z + v.w;
  }
  s[tid] = a;
  __syncthreads();
  for (int st = 128; st > 0; st >>= 1) {
    if (tid < st) s[tid] += s[tid + st];
    __syncthreads();
  }
  if (tid == 0) out[0] = s[0] * invB;
}

extern "C" void kernel_launch(void* const* d_in, const int* in_sizes, int n_in,
                              void* d_out, int out_size, void* d_ws, size_t ws_size,
                              hipStream_t stream) {
  const float* pred    = (const float*)d_in[0];  // [B, T]
  const float* demands = (const float*)d_in[1];  // [B, D]
  const float* cur     = (const float*)d_in[2];  // [B, L]
  const float* caps    = (const float*)d_in[3];  // [L]
  const int*   t2l     = (const int*)d_in[4];    // [T]
  float* out = (float*)d_out;

  const int L = in_sizes[3];          // 16
  const int B = in_sizes[2] / L;      // 16384

  const int grid = B / ROWS_PER_BLOCK;  // 2048
  float* partials = (float*)d_ws;       // grid floats

  rowloss_kernel<<<grid, 256, 0, stream>>>(pred, demands, cur, caps, t2l, partials);
  reduce_kernel<<<1, 256, 0, stream>>>(partials, grid, out, 1.0f / (float)B);
}

// Round 2
// 107.286 us; speedup vs baseline: 1.7018x; 1.7018x over previous
//
#include <hip/hip_runtime.h>

// Problem constants (from reference): B=16384, D=255, K=4, L=16, T=1020
constexpr int T_TUN = 1020;
constexpr int D_DST = 255;
constexpr int L_LNK = 16;
constexpr float EPS = 1e-8f;
constexpr int ROWS_PER_BLOCK = 8;   // 4 waves x 2 rows (concurrent, separate LDS regions)

__device__ __forceinline__ float read_lane_f(float v, int l) {
  return __builtin_bit_cast(float,
      __builtin_amdgcn_readlane(__builtin_bit_cast(int, v), l));
}

__global__ __launch_bounds__(256) void rowloss_kernel(
    const float* __restrict__ pred,     // [B, T]
    const float* __restrict__ demands,  // [B, D]
    const float* __restrict__ cur,      // [B, L]
    const float* __restrict__ caps,     // [L]
    const int*   __restrict__ t2l,      // [T]
    float* __restrict__ partials)       // [gridDim.x]
{
  const int tid  = threadIdx.x;
  const int lane = tid & 63;
  const int w    = tid >> 6;   // wave id 0..3

  // Bin-major per-lane bins: priv[link*64 + lane].
  //  - plain b32 RMW scatter: bank = lane&31 -> 2-way aliasing, free (NOT atomics:
  //    ds_add_f32 measured 4x slower, 1.8M bank-conflict cycles in R1)
  //  - TWO regions per wave (one per row): the two 16-deep may-alias RMW chains
  //    are independent -> scheduler interleaves -> chain latency halved
  //  - column reduce: lane's 16 copies are CONSECUTIVE -> 4x ds_read_b128
  __shared__ float privA_all[4][L_LNK * 64];   // 4 KB/wave
  __shared__ float privB_all[4][L_LNK * 64];   // 4 KB/wave
  __shared__ float wacc[4];
  float* pa = privA_all[w];
  float* pb = privB_all[w];

  const int b16 = lane & 15;       // this lane's bin for the reduce/stats
  const int g   = lane >> 4;       // lane group 0..3
  const float capinv = 1.0f / (caps[b16] + EPS);

  // Row-invariant scatter offsets: element index = link*64 + lane
  int off[4][4];
  bool dv[4];
#pragma unroll
  for (int j = 0; j < 4; ++j) {
    const int d = lane + 64 * j;
    dv[j] = (d < D_DST);
    const int dd = dv[j] ? d : 0;
    const int4 lk = ((const int4*)t2l)[dd];   // t2l[4d..4d+3]
    off[j][0] = lk.x * 64 + lane;
    off[j][1] = lk.y * 64 + lane;
    off[j][2] = lk.z * 64 + lane;
    off[j][3] = lk.w * 64 + lane;
  }

  const int row0 = blockIdx.x * ROWS_PER_BLOCK + w * 2;

  // ---- issue ALL global loads for both rows up front (max MLP) ----
  float4 r4[2][4];
  float  dm[2][4];
  float  mycur[2];
#pragma unroll
  for (int r = 0; r < 2; ++r) {
    const int b = row0 + r;
    const float4* prow = (const float4*)(pred + (size_t)b * T_TUN);
    const float*  drow = demands + (size_t)b * D_DST;
    mycur[r] = cur[(size_t)b * L_LNK + b16];
#pragma unroll
    for (int j = 0; j < 4; ++j) {
      const int d = lane + 64 * j;
      if (dv[j]) { r4[r][j] = prow[d]; dm[r][j] = drow[d]; }
    }
  }

  // zero both regions: 8x ds_write_b128
  {
    const float4 z = make_float4(0.f, 0.f, 0.f, 0.f);
    float4* pza = (float4*)pa;
    float4* pzb = (float4*)pb;
#pragma unroll
    for (int i = 0; i < 4; ++i) { pza[lane + 64 * i] = z; pzb[lane + 64 * i] = z; }
  }

  __builtin_amdgcn_wave_barrier();  // zeroes ordered before scatter (DS pipe in-order)

  // scatter: two independent may-alias RMW chains (row0 -> pa, row1 -> pb),
  // interleaved so their latencies overlap
#pragma unroll
  for (int j = 0; j < 4; ++j) {
    if (!dv[j]) continue;            // only lane63/j3 diverges
    const float4 vA = r4[0][j];
    const float  dA = dm[0][j];
    const float4 vB = r4[1][j];
    const float  dB = dm[1][j];
    pa[off[j][0]] += vA.x * dA;
    pb[off[j][0]] += vB.x * dB;
    pa[off[j][1]] += vA.y * dA;
    pb[off[j][1]] += vB.y * dB;
    pa[off[j][2]] += vA.z * dA;
    pb[off[j][2]] += vB.z * dB;
    pa[off[j][3]] += vA.w * dA;
    pb[off[j][3]] += vB.w * dB;
  }

  __builtin_amdgcn_wave_barrier();  // scatter ordered before reduce reads

  // column reduce both rows: lane's 16 copies (16g..16g+15 of bin b16) = 4x b128 each
  float csA = 0.0f, csB = 0.0f;
  {
    const float4* prA = (const float4*)(pa + b16 * 64 + 16 * g);
    const float4* prB = (const float4*)(pb + b16 * 64 + 16 * g);
#pragma unroll
    for (int q = 0; q < 4; ++q) {
      const float4 a = prA[q];
      csA += a.x + a.y + a.z + a.w;
      const float4 b = prB[q];
      csB += b.x + b.y + b.z + b.w;
    }
  }
  csA += __shfl_xor(csA, 16, 64);
  csA += __shfl_xor(csA, 32, 64);
  csB += __shfl_xor(csB, 16, 64);
  csB += __shfl_xor(csB, 32, 64);

  const float uA = csA * capinv;
  const float uB = csB * capinv;

  // fused stats: group 0 sums u, 1 sums u^2, 2 sums u*cur, 3 maxes u
  float valA = (g == 0) ? uA : (g == 1) ? (uA * uA)
             : (g == 2) ? (uA * mycur[0]) : uA;
  float valB = (g == 0) ? uB : (g == 1) ? (uB * uB)
             : (g == 2) ? (uB * mycur[1]) : uB;
#pragma unroll
  for (int m = 1; m < 16; m <<= 1) {
    const float oA  = __shfl_xor(valA, m, 64);
    const float smA = valA + oA;
    const float mmA = fmaxf(valA, oA);
    valA = (g == 3) ? mmA : smA;
    const float oB  = __shfl_xor(valB, m, 64);
    const float smB = valB + oB;
    const float mmB = fmaxf(valB, oB);
    valB = (g == 3) ? mmB : smB;
  }
  float acc = 0.0f;
  {
    const float s1 = read_lane_f(valA, 0);
    const float s2 = read_lane_f(valA, 16);
    const float s3 = read_lane_f(valA, 32);
    const float mx = read_lane_f(valA, 48);
    const float var = (s2 - s1 * s1 * (1.0f / 16.0f)) * (1.0f / 15.0f); // ddof=1
    acc += 0.3f * var + 0.5f * s3 + 0.2f * mx;
  }
  {
    const float s1 = read_lane_f(valB, 0);
    const float s2 = read_lane_f(valB, 16);
    const float s3 = read_lane_f(valB, 32);
    const float mx = read_lane_f(valB, 48);
    const float var = (s2 - s1 * s1 * (1.0f / 16.0f)) * (1.0f / 15.0f);
    acc += 0.3f * var + 0.5f * s3 + 0.2f * mx;
  }

  if (lane == 0) wacc[w] = acc;
  __syncthreads();
  if (tid == 0) partials[blockIdx.x] = wacc[0] + wacc[1] + wacc[2] + wacc[3];
}

__global__ __launch_bounds__(256) void reduce_kernel(
    const float* __restrict__ partials, int n, float* __restrict__ out, float invB)
{
  __shared__ float s[256];
  const int tid = threadIdx.x;
  const float4* p4 = (const float4*)partials;
  const int n4 = n >> 2;
  float a = 0.0f;
  for (int i = tid; i < n4; i += 256) {
    const float4 v = p4[i];
    a += v.x + v.y + v.z + v.w;
  }
  s[tid] = a;
  __syncthreads();
  for (int st = 128; st > 0; st >>= 1) {
    if (tid < st) s[tid] += s[tid + st];
    __syncthreads();
  }
  if (tid == 0) out[0] = s[0] * invB;
}

extern "C" void kernel_launch(void* const* d_in, const int* in_sizes, int n_in,
                              void* d_out, int out_size, void* d_ws, size_t ws_size,
                              hipStream_t stream) {
  const float* pred    = (const float*)d_in[0];  // [B, T]
  const float* demands = (const float*)d_in[1];  // [B, D]
  const float* cur     = (const float*)d_in[2];  // [B, L]
  const float* caps    = (const float*)d_in[3];  // [L]
  const int*   t2l     = (const int*)d_in[4];    // [T]
  float* out = (float*)d_out;

  const int L = in_sizes[3];          // 16
  const int B = in_sizes[2] / L;      // 16384

  const int grid = B / ROWS_PER_BLOCK;  // 2048
  float* partials = (float*)d_ws;       // grid floats

  rowloss_kernel<<<grid, 256, 0, stream>>>(pred, demands, cur, caps, t2l, partials);
  reduce_kernel<<<1, 256, 0, stream>>>(partials, grid, out, 1.0f / (float)B);
}